// Round 1
// baseline (1347.929 us; speedup 1.0000x reference)
//
#include <hip/hip_runtime.h>
#include <math.h>

#define NQ        14
#define DIM       16384          // 2^14
#define NLAYERS   5
#define NTHREADS  1024
#define PAIRS     (DIM / 2 / NTHREADS)   // 8 pairs per thread per gate
#define AMPS      (DIM / NTHREADS)       // 16 amplitudes per thread

struct c32 { float x, y; };

__device__ __forceinline__ c32 cmul(c32 a, c32 b) {
    return { a.x * b.x - a.y * b.y, a.x * b.y + a.y * b.x };
}

__global__ __launch_bounds__(NTHREADS) void pqc_kernel(
    const float* __restrict__ x,      // (B, 14)
    const float* __restrict__ theta,  // (252,)
    const float* __restrict__ lam,    // (70,)
    const float* __restrict__ w,      // (1, 2)
    float* __restrict__ out)          // (B, 2)
{
    // State vector in LDS: separate real/imag planes (128 KiB total).
    __shared__ float re[DIM];
    __shared__ float im[DIM];
    // Fused variational gates U[l][q] = RZ*RY*RX (shared across batch).
    __shared__ c32 U[NLAYERS + 1][NQ][4];
    // Per-batch fused gates W[l][q] = U[l+1][q] * RX(x*lam).
    __shared__ c32 W[NLAYERS][NQ][4];
    __shared__ float wsum[NTHREADS / 64];

    const int tid = threadIdx.x;
    const int b   = blockIdx.x;

    // ---- Build the 84 variational gate matrices (theta layout: 42*l + 3*q + c) ----
    if (tid < (NLAYERS + 1) * NQ) {
        const int l = tid / NQ, q = tid % NQ;
        const float a0 = theta[3 * tid + 0];   // RX angle
        const float a1 = theta[3 * tid + 1];   // RY angle
        const float a2 = theta[3 * tid + 2];   // RZ angle
        const float cx = cosf(0.5f * a0), sx = sinf(0.5f * a0);
        const float cy = cosf(0.5f * a1), sy = sinf(0.5f * a1);
        const float cz = cosf(0.5f * a2), sz = sinf(0.5f * a2);
        // M = RY @ RX
        const c32 m00 = {  cy * cx,  sy * sx };
        const c32 m01 = { -sy * cx, -cy * sx };
        const c32 m10 = {  sy * cx, -cy * sx };
        const c32 m11 = {  cy * cx, -sy * sx };
        // U = RZ @ M  (row0 *= e^{-i a2/2}, row1 *= e^{+i a2/2})
        const c32 ezm = { cz, -sz }, ezp = { cz, sz };
        U[l][q][0] = cmul(ezm, m00);
        U[l][q][1] = cmul(ezm, m01);
        U[l][q][2] = cmul(ezp, m10);
        U[l][q][3] = cmul(ezp, m11);
    }
    __syncthreads();

    // ---- Fuse encoding RX into the following variational gate ----
    // W[l][q] = U[l+1][q] @ RX(ang),  ang = x[b,q] * lam[l*14+q]
    if (tid < NLAYERS * NQ) {
        const int l = tid / NQ, q = tid % NQ;
        const float ang = x[b * NQ + q] * lam[tid];
        const float c = cosf(0.5f * ang), s = sinf(0.5f * ang);
        const c32 u00 = U[l + 1][q][0], u01 = U[l + 1][q][1];
        const c32 u10 = U[l + 1][q][2], u11 = U[l + 1][q][3];
        // RX = [[c, -i s],[-i s, c]];   (-i s)*z = s*(z.y, -z.x)
        W[l][q][0] = { u00.x * c + s * u01.y,  u00.y * c - s * u01.x };
        W[l][q][1] = { u01.x * c + s * u00.y,  u01.y * c - s * u00.x };
        W[l][q][2] = { u10.x * c + s * u11.y,  u10.y * c - s * u11.x };
        W[l][q][3] = { u11.x * c + s * u10.y,  u11.y * c - s * u10.x };
    }

    // ---- Init |0...0> ----
    for (int k = 0; k < AMPS; ++k) {
        const int idx = tid + k * NTHREADS;
        re[idx] = (idx == 0) ? 1.0f : 0.0f;
        im[idx] = 0.0f;
    }
    __syncthreads();

    // ---- Single-qubit gate on bit position `bit` (bit = 13 - q) ----
    auto gate = [&](const c32* __restrict__ g, int bit) {
        const c32 g00 = g[0], g01 = g[1], g10 = g[2], g11 = g[3];
        const unsigned lo = (1u << bit) - 1u;
        #pragma unroll
        for (int k = 0; k < PAIRS; ++k) {
            const unsigned p  = tid + k * NTHREADS;
            const unsigned i0 = ((p & ~lo) << 1) | (p & lo);
            const unsigned i1 = i0 | (1u << bit);
            const float r0 = re[i0], m0 = im[i0];
            const float r1 = re[i1], m1 = im[i1];
            re[i0] = g00.x * r0 - g00.y * m0 + g01.x * r1 - g01.y * m1;
            im[i0] = g00.x * m0 + g00.y * r0 + g01.x * m1 + g01.y * r1;
            re[i1] = g10.x * r0 - g10.y * m0 + g11.x * r1 - g11.y * m1;
            im[i1] = g10.x * m0 + g10.y * r0 + g11.x * m1 + g11.y * r1;
        }
        __syncthreads();
    };

    // ---- Layer 0: variational gates ----
    for (int q = 0; q < NQ; ++q) gate(U[0][q], NQ - 1 - q);

    // ---- Layers 1..5: ring sign, then fused (encoding+variational) gates ----
    for (int l = 0; l < NLAYERS; ++l) {
        // RING_SIGN: -1 iff parity(popcount(idx & rotl14(idx,1))) is odd
        for (int k = 0; k < AMPS; ++k) {
            const int idx = tid + k * NTHREADS;
            const unsigned rot = ((idx << 1) | ((unsigned)idx >> (NQ - 1))) & (DIM - 1);
            if (__popc(idx & rot) & 1) { re[idx] = -re[idx]; im[idx] = -im[idx]; }
        }
        __syncthreads();
        for (int q = 0; q < NQ; ++q) gate(W[l][q], NQ - 1 - q);
    }

    // ---- Expectation of Z^{\otimes 14} + softmax ----
    float local = 0.0f;
    for (int k = 0; k < AMPS; ++k) {
        const int idx = tid + k * NTHREADS;
        const float rr = re[idx], ii = im[idx];
        const float s = (__popc(idx) & 1) ? -1.0f : 1.0f;
        local += s * (rr * rr + ii * ii);
    }
    #pragma unroll
    for (int off = 32; off > 0; off >>= 1)
        local += __shfl_down(local, off, 64);
    if ((tid & 63) == 0) wsum[tid >> 6] = local;
    __syncthreads();
    if (tid == 0) {
        float v = 0.0f;
        #pragma unroll
        for (int i = 0; i < NTHREADS / 64; ++i) v += wsum[i];
        const float BETA = 1.0f;
        const float l0 = v * w[0] * BETA, l1 = v * w[1] * BETA;
        const float m  = fmaxf(l0, l1);
        const float e0 = __expf(l0 - m), e1 = __expf(l1 - m);
        const float inv = 1.0f / (e0 + e1);
        out[2 * b + 0] = e0 * inv;
        out[2 * b + 1] = e1 * inv;
    }
}

extern "C" void kernel_launch(void* const* d_in, const int* in_sizes, int n_in,
                              void* d_out, int out_size, void* d_ws, size_t ws_size,
                              hipStream_t stream) {
    const float* x     = (const float*)d_in[0];
    const float* theta = (const float*)d_in[1];
    const float* lam   = (const float*)d_in[2];
    const float* w     = (const float*)d_in[3];
    float* out = (float*)d_out;
    const int batch = in_sizes[0] / NQ;   // 2048
    pqc_kernel<<<batch, NTHREADS, 0, stream>>>(x, theta, lam, w, out);
}